// Round 1
// baseline (166.054 us; speedup 1.0000x reference)
//
#include <hip/hip_runtime.h>

#define SEQ 2048
#define HD 64
#define NBH 24
#define TQ 64
#define TK 64
#define KROW 72   // padded bf16 elems per LDS row (144 B stride)
#define SROW 40   // padded S-tile row stride (80 B)

typedef __bf16 bfrag8 __attribute__((ext_vector_type(8)));
typedef __bf16 bf16x4 __attribute__((ext_vector_type(4)));
typedef float floatx4 __attribute__((ext_vector_type(4)));

__device__ __forceinline__ floatx4 mfma_16x16x32(bfrag8 a, bfrag8 b, floatx4 c) {
    return __builtin_amdgcn_mfma_f32_16x16x32_bf16(a, b, c, 0, 0, 0);
}

__global__ __launch_bounds__(256, 4)
void normattn_kernel(const float* __restrict__ qp, const float* __restrict__ kp,
                     const float* __restrict__ vp, const int* __restrict__ maskp,
                     const float* __restrict__ gammap, const float* __restrict__ betap,
                     float* __restrict__ outp)
{
    __shared__ __attribute__((aligned(16))) __bf16 sQ[TQ * KROW];   // [q-local][hd]
    __shared__ __attribute__((aligned(16))) __bf16 sK[TK * KROW];   // [k-local][hd]
    __shared__ __attribute__((aligned(16))) __bf16 sV[HD * KROW];   // V^T: [d][k-local]
    __shared__ __attribute__((aligned(16))) __bf16 sS[4][16 * SROW];// per-wave masked S tile

    const int tid  = threadIdx.x;
    const int wave = tid >> 6;
    const int lane = tid & 63;
    const int quad = lane >> 4;
    const int l16  = lane & 15;
    const int qt   = blockIdx.x;
    const int bh   = blockIdx.y;
    const int q0   = qt * TQ;
    const int base = bh * SEQ * HD;   // fits in int (max ~3.1M floats)

    // ---- stage Q tile: 64x64 fp32 -> bf16 LDS (coalesced float4 reads) ----
    {
        const floatx4* qg = (const floatx4*)(qp + base + q0 * HD);
        #pragma unroll
        for (int it = 0; it < 4; ++it) {
            int idx = tid + it * 256;            // 0..1023
            int r = idx >> 4, c = idx & 15;      // row, float4-col
            floatx4 val = qg[idx];
            bf16x4 pk = { (__bf16)val[0], (__bf16)val[1], (__bf16)val[2], (__bf16)val[3] };
            *(bf16x4*)&sQ[r * KROW + c * 4] = pk;
        }
    }
    __syncthreads();

    // Q A-fragments: A[m=l16][k=quad*8+j (+32h)] — held in regs for whole k-loop
    bfrag8 qa0 = *(const bfrag8*)&sQ[(wave * 16 + l16) * KROW + quad * 8];
    bfrag8 qa1 = *(const bfrag8*)&sQ[(wave * 16 + l16) * KROW + quad * 8 + 32];

    floatx4 acc[4];   // O[q=quad*4+r][d=nt*16+l16]
    #pragma unroll
    for (int i = 0; i < 4; ++i) acc[i] = (floatx4)0.0f;

    const int qrb = q0 + wave * 16 + quad * 4;   // global q base for this lane's S rows

    for (int kb = 0; kb < SEQ; kb += TK) {
        __syncthreads();   // previous iter's sK/sV reads done before restaging

        // ---- stage K tile [64 k][64 hd] ----
        {
            const floatx4* kg = (const floatx4*)(kp + base + kb * HD);
            #pragma unroll
            for (int it = 0; it < 4; ++it) {
                int idx = tid + it * 256;
                int r = idx >> 4, c = idx & 15;
                floatx4 val = kg[idx];
                bf16x4 pk = { (__bf16)val[0], (__bf16)val[1], (__bf16)val[2], (__bf16)val[3] };
                *(bf16x4*)&sK[r * KROW + c * 4] = pk;
            }
        }
        // ---- stage V^T tile [64 d][64 k]: coalesced scalar reads, packed 8B LDS writes ----
        {
            int d = tid & 63;
            #pragma unroll
            for (int it = 0; it < 4; ++it) {
                int k4 = (tid >> 6) + it * 4;    // 0..15
                bf16x4 pk;
                #pragma unroll
                for (int i = 0; i < 4; ++i)
                    pk[i] = (__bf16)vp[base + (kb + k4 * 4 + i) * HD + d];
                *(bf16x4*)&sV[d * KROW + k4 * 4] = pk;
            }
        }
        __syncthreads();

        #pragma unroll
        for (int kc = 0; kc < TK; kc += 32) {
            // ---- S[16q x 32k] = Q(16x64) * K^T(64x32) : 4 MFMAs ----
            floatx4 s0 = (floatx4)0.0f, s1 = (floatx4)0.0f;
            bfrag8 b00 = *(const bfrag8*)&sK[(kc + l16) * KROW + quad * 8];
            bfrag8 b01 = *(const bfrag8*)&sK[(kc + l16) * KROW + quad * 8 + 32];
            bfrag8 b10 = *(const bfrag8*)&sK[(kc + 16 + l16) * KROW + quad * 8];
            bfrag8 b11 = *(const bfrag8*)&sK[(kc + 16 + l16) * KROW + quad * 8 + 32];
            s0 = mfma_16x16x32(qa0, b00, s0);
            s0 = mfma_16x16x32(qa1, b01, s0);
            s1 = mfma_16x16x32(qa0, b10, s1);
            s1 = mfma_16x16x32(qa1, b11, s1);

            // ---- mask in fp32, write bf16 S tile to per-wave LDS (C->A layout bridge) ----
            int kbase = kb + kc + l16;
            #pragma unroll
            for (int r = 0; r < 4; ++r) {
                int mi = (qrb + r) * SEQ + kbase;
                float v0 = maskp[mi]      ? s0[r] : -10000.0f;
                float v1 = maskp[mi + 16] ? s1[r] : -10000.0f;
                sS[wave][(quad * 4 + r) * SROW + l16]      = (__bf16)v0;
                sS[wave][(quad * 4 + r) * SROW + 16 + l16] = (__bf16)v1;
            }
            asm volatile("s_waitcnt lgkmcnt(0)" ::: "memory");

            // ---- O[16q x 64d] += S(16x32) * V(32x64) : 4 MFMAs ----
            bfrag8 pa = *(const bfrag8*)&sS[wave][l16 * SROW + quad * 8];
            #pragma unroll
            for (int nt = 0; nt < 4; ++nt) {
                bfrag8 vb = *(const bfrag8*)&sV[(nt * 16 + l16) * KROW + kc + quad * 8];
                acc[nt] = mfma_16x16x32(pa, vb, acc[nt]);
            }
        }
    }

    // ---- LayerNorm over d=64 per q-row (quad-wide butterfly) + store ----
    float g[4], bt[4];
    #pragma unroll
    for (int nt = 0; nt < 4; ++nt) {
        g[nt]  = gammap[nt * 16 + l16];
        bt[nt] = betap[nt * 16 + l16];
    }
    #pragma unroll
    for (int r = 0; r < 4; ++r) {
        float s = 0.0f, s2 = 0.0f;
        #pragma unroll
        for (int nt = 0; nt < 4; ++nt) { float x = acc[nt][r]; s += x; s2 += x * x; }
        #pragma unroll
        for (int off = 1; off < 16; off <<= 1) {
            s  += __shfl_xor(s, off);
            s2 += __shfl_xor(s2, off);
        }
        float mean = s * (1.0f / 64.0f);
        float var  = s2 * (1.0f / 64.0f) - mean * mean;
        float rstd = rsqrtf(var + 1e-12f);
        int qg2 = qrb + r;
        float* orow = outp + base + qg2 * HD;
        #pragma unroll
        for (int nt = 0; nt < 4; ++nt) {
            int d = nt * 16 + l16;
            orow[d] = (acc[nt][r] - mean) * rstd * g[nt] + bt[nt];
        }
    }
}

extern "C" void kernel_launch(void* const* d_in, const int* in_sizes, int n_in,
                              void* d_out, int out_size, void* d_ws, size_t ws_size,
                              hipStream_t stream) {
    const float* q     = (const float*)d_in[0];
    const float* k     = (const float*)d_in[1];
    const float* v     = (const float*)d_in[2];
    const int*   mask  = (const int*)d_in[3];
    const float* gamma = (const float*)d_in[4];
    const float* beta  = (const float*)d_in[5];
    float* out = (float*)d_out;

    dim3 grid(SEQ / TQ, NBH);   // 32 x 24 = 768 blocks, 256 threads each
    normattn_kernel<<<grid, 256, 0, stream>>>(q, k, v, mask, gamma, beta, out);
}